// Round 9
// baseline (204.881 us; speedup 1.0000x reference)
//
#include <hip/hip_runtime.h>

#define TT 140
#define BB 8192
#define HH 64
#define BTW 32  // batch tile per block = 2 MFMA tiles (ILP-2 per wave)
#define HS 72   // h-array stride in fp16 elems (144 B = 16B-aligned b128 frags)
#define FP ((TT - 1) & 1)   // parity of final step (=1)

typedef _Float16 half8 __attribute__((ext_vector_type(8)));
typedef _Float16 half4 __attribute__((ext_vector_type(4)));
typedef float    f32x4 __attribute__((ext_vector_type(4)));

#define MFMA16(a,b,c) __builtin_amdgcn_mfma_f32_16x16x32_f16(a, b, c, 0, 0, 0)

__device__ __forceinline__ float fast_tanh(float a) {
    float e = __builtin_amdgcn_exp2f(a * 2.88539008178f);
    return 1.0f - 2.0f * __builtin_amdgcn_rcpf(e + 1.0f);
}

__device__ __forceinline__ half8 ld_frag(const _Float16* p) {
    return *(const half8*)__builtin_assume_aligned(p, 16);
}

__device__ __forceinline__ half8 cvt_frag16(const float* p) {
    f32x4 wa = *(const f32x4*)p;
    f32x4 wb = *(const f32x4*)(p + 4);
    half8 h;
    #pragma unroll
    for (int j = 0; j < 8; ++j) h[j] = (_Float16)((j < 4) ? wa[j] : wb[j - 4]);
    return h;
}

// ILP-2 uniform-wave pipeline. Rounds 2/3/5/7 measured VALUBusy pinned ~50%
// across 1/2/4 waves per SIMD: stalls are CORRELATED (barrier-locked phase
// chain + LDS self-sync), so TLP cannot fill them. This version fills them
// with ILP: each wave processes TWO independent 16-batch tiles (grid 256,
// 1 wave/SIMD, 2x work/wave, weights shared across tiles). The y-projection
// is computed from the H1 fragments (which ARE the full h1(p-2) vector) by a
// rotating designated wave and stored directly to global: deletes the 38KB
// pps array (required to fit 2 tiles in static LDS) and the fold epilogue.
__global__ __launch_bounds__(256, 1)
void rnn_kernel(const float* __restrict__ x,
                const float* __restrict__ h_state,
                const float* __restrict__ W_ih0,
                const float* __restrict__ W_hh0,
                const float* __restrict__ b_ih0,
                const float* __restrict__ b_hh0,
                const float* __restrict__ W_ih1,
                const float* __restrict__ W_hh1,
                const float* __restrict__ b_ih1,
                const float* __restrict__ b_hh1,
                const float* __restrict__ W_out,
                const float* __restrict__ b_out,
                float* __restrict__ out)
{
    __shared__ __align__(16) _Float16 h0f[2][2][16 * HS];  // [parity][tile][...]
    __shared__ __align__(16) _Float16 h1f[2][2][16 * HS];
    __shared__ float xs[TT * 33];        // x staged [t][b], b=0..31

    const int tid  = threadIdx.x;
    const int wl   = tid >> 6;        // 0..3 = unit-quarter
    const int lane = tid & 63;
    const int col  = lane & 15;       // MFMA col (batch within tile)
    const int q    = lane >> 4;       // quad
    const int b0   = blockIdx.x * BTW;

    // ---- A-fragments (fp16): rows 16wl+col of Whh0 / Wih1 / Whh1 ----
    half8 A0[2], AI[2], AH[2];
    #pragma unroll
    for (int kt = 0; kt < 2; ++kt) {
        const int off = (16 * wl + col) * HH + 32 * kt + 8 * q;
        A0[kt] = cvt_frag16(W_hh0 + off);
        AI[kt] = cvt_frag16(W_ih1 + off);
        AH[kt] = cvt_frag16(W_hh1 + off);
    }
    // epilogue scalars for this wave's quarter (units 16wl+4q+r)
    float e00[4], e10[4], e01[4];
    #pragma unroll
    for (int r = 0; r < 4; ++r) {
        int j = 16 * wl + 4 * q + r;
        e00[r] = b_ih0[j] + b_hh0[j];  e10[r] = W_ih0[j];
        e01[r] = b_ih1[j] + b_hh1[j];
    }
    // W_out in H1-fragment layout: lane needs k = 8q+j and 32+8q+j
    float WO[16];
    #pragma unroll
    for (int j = 0; j < 8; ++j) {
        WO[j]     = W_out[8 * q + j];
        WO[8 + j] = W_out[32 + 8 * q + j];
    }
    const float bout = b_out[0];

    // ---- stage x[b0..b0+31][0..139] into LDS [t][b] (256 threads) ----
    for (int c = 0; c < (TT * BTW + 255) / 256; ++c) {
        int i = c * 256 + tid;
        if (i < TT * BTW) {
            int t = i >> 5, b = i & 31;
            xs[t * 33 + b] = x[(size_t)(b0 + b) * TT + t];
        }
    }
    // ---- init hidden state ([2,B,H]) into parity-1 buffers (step "-1") ----
    #pragma unroll
    for (int c = 0; c < (BTW * HH) / 256; ++c) {
        int i = c * 256 + tid;
        int b = i >> 6, u = i & 63;
        int tl = b >> 4, cc = b & 15;
        h0f[1][tl][cc * HS + u] = (_Float16)h_state[(size_t)(b0 + b) * HH + u];
        h1f[1][tl][cc * HS + u] = (_Float16)h_state[(size_t)BB * HH + (size_t)(b0 + b) * HH + u];
    }
    __syncthreads();

    // ---- pipelined phase loop: p=0..TT+1 ----
    for (int p = 0; p <= TT + 1; ++p) {
        const int rb = (p + 1) & 1;   // h0(p-1) read parity == h1(p-1) write parity
        const int wb = p & 1;         // h0(p) write parity == h1(p-2) read parity
        half8 H0a[2], H0b[2], H1a[2], H1b[2];
        float xt[2];
        // H1 frags (h1(p-2)): feed both L1's hh matmul and the projection
        #pragma unroll
        for (int tl = 0; tl < 2; ++tl) {
            H1a[tl] = ld_frag(&h1f[wb][tl][col * HS + 8 * q]);
            H1b[tl] = ld_frag(&h1f[wb][tl][col * HS + 32 + 8 * q]);
        }
        if (p <= TT) {
            // H0 frags (h0(p-1) = h0n(p-1)): feed L0's recurrence AND L1's ih1
            #pragma unroll
            for (int tl = 0; tl < 2; ++tl) {
                H0a[tl] = ld_frag(&h0f[rb][tl][col * HS + 8 * q]);
                H0b[tl] = ld_frag(&h0f[rb][tl][col * HS + 32 + 8 * q]);
                xt[tl]  = xs[p * 33 + 16 * tl + col];
            }
        }
        if (p < TT) {
            // layer0 step p (both tiles): h0n = tanh(Whh0*h0 + b + Wih0*x)
            #pragma unroll
            for (int tl = 0; tl < 2; ++tl) {
                f32x4 c = {0.f, 0.f, 0.f, 0.f};
                c = MFMA16(A0[0], H0a[tl], c);
                c = MFMA16(A0[1], H0b[tl], c);
                half4 h4;
                #pragma unroll
                for (int r = 0; r < 4; ++r) {
                    float pre = c[r] + e00[r] + e10[r] * xt[tl];
                    h4[r] = (_Float16)fast_tanh(pre);
                }
                *(half4*)(&h0f[wb][tl][col * HS + 16 * wl + 4 * q]) = h4;
            }
        }
        if (p >= 1 && p <= TT) {
            // layer1 step s=p-1 (both tiles): reuses H0 (= h0n(s)) and H1 (= h1(s-1))
            #pragma unroll
            for (int tl = 0; tl < 2; ++tl) {
                f32x4 ci = {0.f, 0.f, 0.f, 0.f}, ch = {0.f, 0.f, 0.f, 0.f};
                ci = MFMA16(AI[0], H0a[tl], ci);
                ci = MFMA16(AI[1], H0b[tl], ci);
                ch = MFMA16(AH[0], H1a[tl], ch);
                ch = MFMA16(AH[1], H1b[tl], ch);
                f32x4 a = ci + ch;
                half4 h4;
                #pragma unroll
                for (int r = 0; r < 4; ++r)
                    h4[r] = (_Float16)fast_tanh(a[r] + e01[r]);
                *(half4*)(&h1f[rb][tl][col * HS + 16 * wl + 4 * q]) = h4;
            }
        }
        if (p >= 2 && wl == ((p - 2) & 3)) {
            // y[:, p-2] = Wout . h1(p-2) + bout, straight from the H1 frags
            #pragma unroll
            for (int tl = 0; tl < 2; ++tl) {
                float pr = 0.f;
                #pragma unroll
                for (int j = 0; j < 8; ++j) {
                    pr += WO[j]     * (float)H1a[tl][j];
                    pr += WO[8 + j] * (float)H1b[tl][j];
                }
                pr += __shfl_xor(pr, 16, 64);
                pr += __shfl_xor(pr, 32, 64);
                if (lane < 16)
                    out[(size_t)(b0 + 16 * tl + lane) * TT + (p - 2)] = pr + bout;
            }
        }
        __syncthreads();
    }

    // ---- h_final: [2,B,H] appended after out[B*T]; final parity FP ----
    const size_t OFF = (size_t)BB * TT;
    #pragma unroll
    for (int c = 0; c < (BTW * HH) / 256; ++c) {
        int i = c * 256 + tid;
        int b = i >> 6, u = i & 63;
        int tl = b >> 4, cc = b & 15;
        out[OFF + (size_t)(b0 + b) * HH + u] = (float)h0f[FP][tl][cc * HS + u];
        out[OFF + (size_t)BB * HH + (size_t)(b0 + b) * HH + u] = (float)h1f[FP][tl][cc * HS + u];
    }
}

extern "C" void kernel_launch(void* const* d_in, const int* in_sizes, int n_in,
                              void* d_out, int out_size, void* d_ws, size_t ws_size,
                              hipStream_t stream) {
    const float* x      = (const float*)d_in[0];
    const float* hst    = (const float*)d_in[1];
    const float* W_ih0  = (const float*)d_in[2];
    const float* W_hh0  = (const float*)d_in[3];
    const float* b_ih0  = (const float*)d_in[4];
    const float* b_hh0  = (const float*)d_in[5];
    const float* W_ih1  = (const float*)d_in[6];
    const float* W_hh1  = (const float*)d_in[7];
    const float* b_ih1  = (const float*)d_in[8];
    const float* b_hh1  = (const float*)d_in[9];
    const float* W_out  = (const float*)d_in[10];
    const float* b_outp = (const float*)d_in[11];
    float* out = (float*)d_out;

    dim3 grid(BB / BTW);  // 256 blocks x 4 waves: 1 block/CU, 1 wave/SIMD, ILP-2
    dim3 block(256);
    rnn_kernel<<<grid, block, 0, stream>>>(x, hst, W_ih0, W_hh0, b_ih0, b_hh0,
                                           W_ih1, W_hh1, b_ih1, b_hh1,
                                           W_out, b_outp, out);
}